// Round 2
// baseline (78.655 us; speedup 1.0000x reference)
//
#include <hip/hip_runtime.h>
#include <stdint.h>

#define NROWS 8192
#define NDIM 128
#define NB 64                        // 8192/128 row-blocks
#define NBLOCKS (NB * (NB + 1) / 2)  // 2080 lower-triangular blocks
#define NSLOTS 64

typedef short s16x8 __attribute__((ext_vector_type(8)));
typedef float f32x4 __attribute__((ext_vector_type(4)));

__device__ __forceinline__ uint32_t f32_to_bf16_rne(float x) {
    uint32_t u = __float_as_uint(x);
    return (u + 0x7FFFu + ((u >> 16) & 1u)) >> 16;
}

// One wave per row: f32 load, L2-norm via shfl reduce, bf16 store (packed u32).
// Block 0 additionally zeroes the 64 partial-sum slots and computes the
// labels-are-int64 flag (all odd int32 words zero for values 0..99).
__global__ __launch_bounds__(256) void normalize_kernel(const float* __restrict__ feat,
                                                        uint32_t* __restrict__ fhat,
                                                        const int* __restrict__ labels,
                                                        float* __restrict__ slots,
                                                        int* __restrict__ flag) {
    if (blockIdx.x == 0) {
        if (threadIdx.x < NSLOTS) slots[threadIdx.x] = 0.0f;
        if (threadIdx.x == 0) {
            int is64 = 1;
            for (int i = 0; i < 64; ++i)
                if (labels[2 * i + 1] != 0) { is64 = 0; break; }
            flag[0] = is64;
        }
    }
    int wave = threadIdx.x >> 6;
    int lane = threadIdx.x & 63;
    int row = blockIdx.x * 4 + wave;
    const float2* src = reinterpret_cast<const float2*>(feat) + row * 64 + lane;
    float2 v = *src;
    float ss = v.x * v.x + v.y * v.y;
#pragma unroll
    for (int off = 32; off; off >>= 1) ss += __shfl_xor(ss, off);
    float sc = 1.0f / fmaxf(sqrtf(ss), 1e-12f);
    fhat[row * 64 + lane] = (f32_to_bf16_rne(v.y * sc) << 16) | f32_to_bf16_rne(v.x * sc);
}

// One 128x128 tile of S = F̂ F̂^T per block (lower triangle only).
// No LDS, no barriers: each lane loads its 16B MFMA fragments directly from
// global (fhat = 2 MB, L2-resident). Fused mask+relu+reduce epilogue.
__global__ __launch_bounds__(256) void shadow_gemm(const uint32_t* __restrict__ fhat,
                                                   const int* __restrict__ labels,
                                                   const int* __restrict__ flag,
                                                   float* __restrict__ slots) {
    // triangular block decode: t -> (bi, bj), bi >= bj
    int t = blockIdx.x;
    int bi = (int)((sqrtf(8.0f * (float)t + 1.0f) - 1.0f) * 0.5f);
    while ((bi + 1) * (bi + 2) / 2 <= t) ++bi;
    while (bi * (bi + 1) / 2 > t) --bi;
    int bj = t - bi * (bi + 1) / 2;

    int lane = threadIdx.x & 63;
    int wave = threadIdx.x >> 6;
    int wm = wave >> 1, wn = wave & 1;  // 2x2 wave grid, 64x64 per wave

    const char* base = (const char*)fhat;
    int ra = bi * 128 + wm * 64 + (lane & 15);      // A fragment row (+16*mi)
    int rb = bj * 128 + wn * 64 + (lane & 15);      // B fragment row (+16*ni)
    int kc = (lane >> 4) << 4;                      // byte offset of lane's 8-elem k-group

    f32x4 acc[4][4];
#pragma unroll
    for (int mi = 0; mi < 4; ++mi)
#pragma unroll
        for (int ni = 0; ni < 4; ++ni) acc[mi][ni] = f32x4{0.f, 0.f, 0.f, 0.f};

#pragma unroll
    for (int ks = 0; ks < 4; ++ks) {                // 4 K-steps of 32
        int cb = ks * 64 + kc;
        s16x8 a[4], b[4];
#pragma unroll
        for (int mi = 0; mi < 4; ++mi)
            a[mi] = *reinterpret_cast<const s16x8*>(base + (ra + mi * 16) * 256 + cb);
#pragma unroll
        for (int ni = 0; ni < 4; ++ni)
            b[ni] = *reinterpret_cast<const s16x8*>(base + (rb + ni * 16) * 256 + cb);
#pragma unroll
        for (int mi = 0; mi < 4; ++mi)
#pragma unroll
            for (int ni = 0; ni < 4; ++ni)
                acc[mi][ni] = __builtin_amdgcn_mfma_f32_16x16x32_bf16(a[mi], b[ni],
                                                                      acc[mi][ni], 0, 0, 0);
    }

    // Epilogue: per-element mask + relu, reduce to scalar.
    int shl = flag[0];  // 1 if labels are int64 (stride-2 int32 view), else 0
    int labr[16];
#pragma unroll
    for (int mi = 0; mi < 4; ++mi)
#pragma unroll
        for (int rr = 0; rr < 4; ++rr) {
            int gi = bi * 128 + wm * 64 + mi * 16 + ((lane >> 4) << 2) + rr;
            labr[mi * 4 + rr] = labels[gi << shl];
        }

    float lsum = 0.0f;
#pragma unroll
    for (int ni = 0; ni < 4; ++ni) {
        int gj = bj * 128 + wn * 64 + ni * 16 + (lane & 15);
        int labj = labels[gj << shl];
#pragma unroll
        for (int mi = 0; mi < 4; ++mi) {
#pragma unroll
            for (int rr = 0; rr < 4; ++rr) {
                int gi = bi * 128 + wm * 64 + mi * 16 + ((lane >> 4) << 2) + rr;
                float s = acc[mi][ni][rr];
                // pos: relu(10s-9); neg: relu(11-10s)
                float v = (labr[mi * 4 + rr] == labj)
                              ? fmaxf(fmaf(10.0f, s, -9.0f), 0.0f)
                              : fmaxf(fmaf(-10.0f, s, 11.0f), 0.0f);
                lsum += (gi != gj) ? v : 0.0f;  // exclude diagonal
            }
        }
    }
    float wgt = (bi == bj) ? 1.0f : 2.0f;   // off-diag tiles cover (i,j) and (j,i)
    lsum *= wgt * (1.0f / 67100672.0f);     // 8192*8191 exact in f32

#pragma unroll
    for (int off = 32; off; off >>= 1) lsum += __shfl_xor(lsum, off);
    if (lane == 0) atomicAdd(&slots[(t * 4 + wave) & (NSLOTS - 1)], lsum);
}

__global__ void finalize_kernel(const float* __restrict__ slots, float* __restrict__ out) {
    float v = slots[threadIdx.x];  // 64 threads
#pragma unroll
    for (int off = 32; off; off >>= 1) v += __shfl_xor(v, off);
    if (threadIdx.x == 0) out[0] = v;
}

extern "C" void kernel_launch(void* const* d_in, const int* in_sizes, int n_in,
                              void* d_out, int out_size, void* d_ws, size_t ws_size,
                              hipStream_t stream) {
    const float* feat = (const float*)d_in[0];
    const int* labels = (const int*)d_in[1];
    float* out = (float*)d_out;
    uint32_t* fhat = (uint32_t*)d_ws;  // 8192*128 bf16 = 2 MB
    float* slots = (float*)((char*)d_ws + (size_t)NROWS * NDIM * 2);
    int* flag = (int*)(slots + NSLOTS);

    normalize_kernel<<<NROWS / 4, 256, 0, stream>>>(feat, fhat, labels, slots, flag);
    shadow_gemm<<<NBLOCKS, 256, 0, stream>>>(fhat, labels, flag, slots);
    finalize_kernel<<<1, 64, 0, stream>>>(slots, out);
}

// Round 3
// 30.538 us; speedup vs baseline: 2.5756x; 2.5756x over previous
//
#include <hip/hip_runtime.h>
#include <stdint.h>

#define NROWS 8192
#define NDIM 128
#define NBK1 256                    // row-blocks in k1 (32 rows each)
#define ROWS_PER_BLK (NROWS / NBK1) // 32
#define NCLS 100

typedef short s16x8 __attribute__((ext_vector_type(8)));
typedef float f32x4 __attribute__((ext_vector_type(4)));
typedef __attribute__((address_space(3))) uint32_t lds_u32_t;
typedef __attribute__((address_space(1))) const uint32_t glb_u32_t;

// ws byte offsets
#define WS_FHAT  0u         // 8192*128 bf16 = 2 MB
#define WS_PG    2097152u   // 256 x 128 f32 partial g
#define WS_PA    2228224u   // 256 f32 partial anchor sums
#define WS_IDX   2229248u   // 8192 int (class-sorted row indices)
#define WS_CNT   2262016u   // 100 int class counts (pad to 512)
#define WS_OFF   2262528u   // 100 int class offsets (pad to 512)
#define WS_META  2263040u   // [0]=Npos_offdiag, [1]=||g||^2, [2]=sum anchors
#define WS_SLOT  2263104u   // 100 x {prelu, spos} f32

__device__ __forceinline__ uint32_t f32_to_bf16_rne(float x) {
    uint32_t u = __float_as_uint(x);
    return (u + 0x7FFFu + ((u >> 16) & 1u)) >> 16;
}

// Blocks 0..255: normalize 32 rows each -> fhat (bf16), partial g, partial anchor.
// Block 256: label histogram + prefix + scatter (class index lists) + Npos.
__global__ __launch_bounds__(256) void k1_normalize_sort(const float* __restrict__ feat,
                                                         const int* __restrict__ labels,
                                                         char* __restrict__ ws) {
    int tid = threadIdx.x;
    if (blockIdx.x == NBK1) {
        __shared__ int hist[NCLS];
        __shared__ int offs[NCLS];
        __shared__ int shl_s;
        if (tid == 0) {  // detect int64 labels (all odd words of first 64 zero)
            int is64 = 1;
            for (int i = 0; i < 64; ++i)
                if (labels[2 * i + 1] != 0) { is64 = 0; break; }
            shl_s = is64;
        }
        for (int i = tid; i < NCLS; i += 256) hist[i] = 0;
        __syncthreads();
        int shl = shl_s;
        for (int i = tid; i < NROWS; i += 256) atomicAdd(&hist[labels[i << shl]], 1);
        __syncthreads();
        if (tid == 0) {
            int acc = 0; unsigned npos = 0;
            for (int c = 0; c < NCLS; ++c) {
                offs[c] = acc;
                int nc = hist[c];
                npos += (unsigned)nc * (unsigned)nc;
                acc += nc;
            }
            ((float*)(ws + WS_META))[0] = (float)npos - (float)NROWS;  // Npos off-diag
        }
        __syncthreads();
        int* gcnt = (int*)(ws + WS_CNT);
        int* goff = (int*)(ws + WS_OFF);
        for (int i = tid; i < NCLS; i += 256) { gcnt[i] = hist[i]; goff[i] = offs[i]; }
        __syncthreads();   // goff stores read offs before scatter mutates it
        int* gidx = (int*)(ws + WS_IDX);
        for (int i = tid; i < NROWS; i += 256) {
            int c = labels[i << shl];
            int p = atomicAdd(&offs[c], 1);
            gidx[p] = i;
        }
        return;
    }
    int wave = tid >> 6, lane = tid & 63;
    const float2* fp = (const float2*)feat;
    uint32_t* fhat = (uint32_t*)(ws + WS_FHAT);
    float gx = 0.f, gy = 0.f, aacc = 0.f;
    int rbase = blockIdx.x * ROWS_PER_BLK;
#pragma unroll
    for (int k = 0; k < ROWS_PER_BLK / 4; ++k) {
        int row = rbase + k * 4 + wave;
        float2 v = fp[row * 64 + lane];
        float ss = v.x * v.x + v.y * v.y;
#pragma unroll
        for (int o = 32; o; o >>= 1) ss += __shfl_xor(ss, o);
        float sc = 1.0f / fmaxf(sqrtf(ss), 1e-12f);
        float fx = v.x * sc, fy = v.y * sc;
        gx += fx; gy += fy;
        aacc += ss * sc * sc;  // ||f_hat||^2 (anchor)
        fhat[row * 64 + lane] = (f32_to_bf16_rne(fy) << 16) | f32_to_bf16_rne(fx);
    }
    __shared__ float gbuf[4][128];
    __shared__ float abuf[4];
    gbuf[wave][lane * 2] = gx;
    gbuf[wave][lane * 2 + 1] = gy;
    if (lane == 0) abuf[wave] = aacc;
    __syncthreads();
    float* pg = (float*)(ws + WS_PG) + blockIdx.x * NDIM;
    if (wave == 0) {
        float s0 = gbuf[0][lane*2]   + gbuf[1][lane*2]   + gbuf[2][lane*2]   + gbuf[3][lane*2];
        float s1 = gbuf[0][lane*2+1] + gbuf[1][lane*2+1] + gbuf[2][lane*2+1] + gbuf[3][lane*2+1];
        ((float2*)pg)[lane] = float2{s0, s1};
    }
    if (tid == 0) ((float*)(ws + WS_PA))[blockIdx.x] = abuf[0] + abuf[1] + abuf[2] + abuf[3];
}

// Blocks 0..99: within-class pairwise via one (or more) 128x128 MFMA tiles over
// gathered rows. Block 100: reduce partial g -> ||g||^2 and partial anchors.
__global__ __launch_bounds__(256) void k4_classes(char* __restrict__ ws) {
    __shared__ __align__(16) char sm[65536];
    int tid = threadIdx.x;
    if (blockIdx.x == NCLS) {
        const float* pg = (const float*)(ws + WS_PG);
        const float* pa = (const float*)(ws + WS_PA);
        float acc = 0.f;
        if (tid < NDIM)
            for (int b = 0; b < NBK1; ++b) acc += pg[b * NDIM + tid];
        float sq = acc * acc;
        float av = pa[tid];  // NBK1 == 256 == blockDim
#pragma unroll
        for (int o = 32; o; o >>= 1) { sq += __shfl_xor(sq, o); av += __shfl_xor(av, o); }
        float* r2 = (float*)sm;
        if ((tid & 63) == 0) { r2[(tid >> 6) * 2] = sq; r2[(tid >> 6) * 2 + 1] = av; }
        __syncthreads();
        if (tid == 0) {
            float* meta = (float*)(ws + WS_META);
            meta[1] = r2[0] + r2[2] + r2[4] + r2[6];
            meta[2] = r2[1] + r2[3] + r2[5] + r2[7];
        }
        return;
    }
    int c = blockIdx.x;
    int n   = ((const int*)(ws + WS_CNT))[c];
    int off = ((const int*)(ws + WS_OFF))[c];
    const int* gidx = (const int*)(ws + WS_IDX);
    const char* fhat = ws + WS_FHAT;
    int lane = tid & 63, wave = tid >> 6;
    int wm = wave >> 1, wn = wave & 1;
    float prelu = 0.f, spos = 0.f;
    int ntiles = (n + 127) >> 7;
    for (int ti = 0; ti < ntiles; ++ti)
        for (int tj = 0; tj < ntiles; ++tj) {
            __syncthreads();
            // stage gathered rows: linear LDS dest, inverse-swizzled per-lane src
            int r16 = tid >> 4;
            uint32_t cst = (uint32_t)((tid & 15) << 4);
#pragma unroll
            for (int it = 0; it < 8; ++it) {
                int row = it * 16 + r16;
                uint32_t csrc = cst ^ (uint32_t)((row & 7) << 4);
                int pa_ = ti * 128 + row;
                int pb_ = tj * 128 + row;
                int ra = gidx[off + ((pa_ < n) ? pa_ : 0)];   // clamp: masked later
                int rb = gidx[off + ((pb_ < n) ? pb_ : 0)];
                uint32_t l = (uint32_t)(it * 4096 + tid * 16);
                __builtin_amdgcn_global_load_lds((glb_u32_t*)(fhat + ra * 256 + csrc),
                                                 (lds_u32_t*)(sm + l), 16, 0, 0);
                __builtin_amdgcn_global_load_lds((glb_u32_t*)(fhat + rb * 256 + csrc),
                                                 (lds_u32_t*)(sm + 32768 + l), 16, 0, 0);
            }
            __syncthreads();
            int rb_ = lane & 15;
            uint32_t kcol = (uint32_t)((lane >> 4) << 4);
            f32x4 acc[4][4];
#pragma unroll
            for (int mi = 0; mi < 4; ++mi)
#pragma unroll
                for (int ni = 0; ni < 4; ++ni) acc[mi][ni] = f32x4{0.f, 0.f, 0.f, 0.f};
#pragma unroll
            for (int ks = 0; ks < 4; ++ks) {
                uint32_t c2 = (uint32_t)(ks * 64) + kcol;
                s16x8 a[4], b[4];
#pragma unroll
                for (int mi = 0; mi < 4; ++mi) {
                    int r = wm * 64 + mi * 16 + rb_;
                    uint32_t ad = (uint32_t)(r * 256) + (c2 ^ (uint32_t)((r & 7) << 4));
                    a[mi] = *reinterpret_cast<const s16x8*>(sm + ad);
                }
#pragma unroll
                for (int ni = 0; ni < 4; ++ni) {
                    int r = wn * 64 + ni * 16 + rb_;
                    uint32_t ad = (uint32_t)(r * 256) + (c2 ^ (uint32_t)((r & 7) << 4));
                    b[ni] = *reinterpret_cast<const s16x8*>(sm + 32768 + ad);
                }
#pragma unroll
                for (int mi = 0; mi < 4; ++mi)
#pragma unroll
                    for (int ni = 0; ni < 4; ++ni)
                        acc[mi][ni] = __builtin_amdgcn_mfma_f32_16x16x32_bf16(
                            a[mi], b[ni], acc[mi][ni], 0, 0, 0);
            }
#pragma unroll
            for (int ni = 0; ni < 4; ++ni) {
                int jp = tj * 128 + wn * 64 + ni * 16 + rb_;
#pragma unroll
                for (int mi = 0; mi < 4; ++mi)
#pragma unroll
                    for (int rr = 0; rr < 4; ++rr) {
                        int ip = ti * 128 + wm * 64 + mi * 16 + ((lane >> 4) << 2) + rr;
                        bool v = (ip < n) && (jp < n) && (ip != jp);
                        float s = acc[mi][ni][rr];
                        prelu += v ? fmaxf(fmaf(10.f, s, -9.f), 0.f) : 0.f;
                        spos  += v ? s : 0.f;
                    }
            }
        }
#pragma unroll
    for (int o = 32; o; o >>= 1) { prelu += __shfl_xor(prelu, o); spos += __shfl_xor(spos, o); }
    __syncthreads();   // tiles dead; reuse sm for the block reduce
    float* rs = (float*)sm;
    if (lane == 0) { rs[wave * 2] = prelu; rs[wave * 2 + 1] = spos; }
    __syncthreads();
    if (tid == 0) {
        float* slot = (float*)(ws + WS_SLOT);
        slot[c * 2]     = rs[0] + rs[2] + rs[4] + rs[6];
        slot[c * 2 + 1] = rs[1] + rs[3] + rs[5] + rs[7];
    }
}

// loss = (P_relu + 11*Nneg - 10*(S_all_off - S_pos_off)) / count
__global__ void k5_final(const char* __restrict__ ws, float* __restrict__ out) {
    int lane = threadIdx.x;  // 64 threads
    const float* slot = (const float*)(ws + WS_SLOT);
    float pr = 0.f, sp = 0.f;
    for (int i = lane; i < NCLS; i += 64) { pr += slot[2 * i]; sp += slot[2 * i + 1]; }
#pragma unroll
    for (int o = 32; o; o >>= 1) { pr += __shfl_xor(pr, o); sp += __shfl_xor(sp, o); }
    if (lane == 0) {
        const float* meta = (const float*)(ws + WS_META);
        double nposoff = (double)meta[0];
        double g2      = (double)meta[1];
        double sa      = (double)meta[2];
        double count = 8192.0 * 8191.0;
        double nneg = count - nposoff;
        double sall = g2 - sa;                 // sum_{i != j} s_ij
        double sneg = sall - (double)sp;
        double loss = ((double)pr + 11.0 * nneg - 10.0 * sneg) / count;
        out[0] = (float)loss;
    }
}

extern "C" void kernel_launch(void* const* d_in, const int* in_sizes, int n_in,
                              void* d_out, int out_size, void* d_ws, size_t ws_size,
                              hipStream_t stream) {
    const float* feat = (const float*)d_in[0];
    const int* labels = (const int*)d_in[1];
    float* out = (float*)d_out;
    char* ws = (char*)d_ws;

    k1_normalize_sort<<<NBK1 + 1, 256, 0, stream>>>(feat, labels, ws);
    k4_classes<<<NCLS + 1, 256, 0, stream>>>(ws);
    k5_final<<<1, 64, 0, stream>>>(ws, out);
}